// Round 7
// baseline (483.251 us; speedup 1.0000x reference)
//
#include <hip/hip_runtime.h>
#include <hip/hip_fp16.h>
#include <hip/hip_cooperative_groups.h>
#include <math.h>

namespace cg = cooperative_groups;

#define TBINS   50000
#define NR      4
#define RBINS   12500          // TBINS / NR
#define NS      64             // slices
#define NBLK    256            // NR * NS, 1 block/CU
#define PTHR    1024
#define NG2     49             // ceil(TBINS / 1024) blocks active in phases C/D
#define EPSF    1e-7f

// ---- ws layout (byte offsets) ----
#define OFF_SCAL  0            // dbl[2]: [0]=sum lr over events, [1]=log-sum
#define OFF_NEV   16           // int
#define OFF_GSUM  64           // f32[NG2]
#define OFF_LRP   512          // f32[NBLK]
#define OFF_NP    1536         // i32[NBLK]
#define OFF_PACK  4096         // u32[N]
#define SLICE_AB  0            // u32[TBINS]: f16(all) | f16(ev)<<16
#define SLICE_CNT 200000       // u8[TBINS]
#define PER_SLICE 262144

__global__ __launch_bounds__(PTHR) void k_fused(
        const float* __restrict__ lr, const int* __restrict__ tm,
        const int* __restrict__ ev, int N, char* __restrict__ ws,
        float* __restrict__ out) {
    __shared__ float    s_all[RBINS];
    __shared__ unsigned s_evcnt[RBINS];   // (count<<28) | fixed12.16(sum exp over events)
    __shared__ float    red_f[16];
    __shared__ int      red_i[16];
    __shared__ float    sh_base;

    cg::grid_group grid = cg::this_grid();
    const int bid  = blockIdx.x;
    const int tid  = threadIdx.x;
    const int lane = tid & 63, wv = tid >> 6;

    unsigned* packed   = (unsigned*)(ws + OFF_PACK);
    size_t    off_sl   = ((size_t)OFF_PACK + (size_t)N * 4 + 255) & ~(size_t)255;
    char*     slices   = ws + off_sl;
    double*   scal     = (double*)(ws + OFF_SCAL);
    int*      nev      = (int*)(ws + OFF_NEV);
    float*    gsum     = (float*)(ws + OFF_GSUM);
    float*    lrp      = (float*)(ws + OFF_LRP);
    int*      np       = (int*)(ws + OFF_NP);

    // zero LDS histogram (used in phase B)
    for (int i = tid; i < RBINS; i += PTHR) { s_all[i] = 0.f; s_evcnt[i] = 0u; }

    // ================= phase A: pack (time<<16)|f16(exp(lr)) with event sign =================
    int CHA = ((N + NBLK * 4 - 1) / (NBLK * 4)) * 4;
    int beginA = bid * CHA;
    int endA   = beginA + CHA; if (endA > N) endA = N;
    float l_lr = 0.f; int l_n = 0;

#define PACK1(L, TT, E, OUT) {                                            \
        float r_ = __expf(L);                                             \
        unsigned hb_ = (unsigned)__half_as_ushort(__float2half(r_));      \
        if ((E) != 0) { hb_ |= 0x8000u; l_lr += (L); l_n++; }             \
        OUT = ((unsigned)(TT) << 16) | hb_; }

    for (int base = beginA + tid * 4; base + 3 < endA; base += PTHR * 4) {
        float4 l4 = *(const float4*)(lr + base);
        int4   t4 = *(const int4*)(tm + base);
        int4   e4 = *(const int4*)(ev + base);
        uint4 o;
        PACK1(l4.x, t4.x, e4.x, o.x)
        PACK1(l4.y, t4.y, e4.y, o.y)
        PACK1(l4.z, t4.z, e4.z, o.z)
        PACK1(l4.w, t4.w, e4.w, o.w)
        *(uint4*)(packed + base) = o;
    }
    {   // scalar tail (empty for N % 4 == 0)
        int spanA = endA - beginA; if (spanA < 0) spanA = 0;
        for (int i = beginA + (spanA & ~3) + tid; i < endA; i += PTHR) {
            unsigned o;
            PACK1(lr[i], tm[i], ev[i], o)
            packed[i] = o;
        }
    }
    #pragma unroll
    for (int off = 32; off > 0; off >>= 1) {
        l_lr += __shfl_down(l_lr, off, 64);
        l_n  += __shfl_down(l_n,  off, 64);
    }
    if (lane == 0) { red_f[wv] = l_lr; red_i[wv] = l_n; }
    __syncthreads();
    if (tid == 0) {
        float s = 0.f; int c = 0;
        #pragma unroll
        for (int w = 0; w < 16; ++w) { s += red_f[w]; c += red_i[w]; }
        lrp[bid] = s; np[bid] = c;
    }
    __threadfence();
    grid.sync();

    // ================= phase B: LDS histogram over packed (XCD-swizzled) =================
    {
        int x = bid & 7, q = bid >> 3;
        int range = q & 3;
        int slice = (q >> 2) * 8 + x;     // 4 range-blocks of a slice share an XCD
        unsigned rbase = (unsigned)(range * RBINS);
        int CH    = ((N + NS * 4 - 1) / (NS * 4)) * 4;
        int begin = slice * CH;
        int end   = begin + CH; if (end > N) end = N;
        int span  = end - begin; if (span < 0) span = 0;

#define PROC1(P) {                                                        \
        unsigned rel_ = ((P) >> 16) - rbase;                              \
        if (rel_ < (unsigned)RBINS) {                                     \
            float r_ = __half2float(__ushort_as_half((unsigned short)((P) & 0x7FFFu))); \
            atomicAdd(&s_all[rel_], r_);                                  \
            if ((P) & 0x8000u) {                                          \
                unsigned enc_ = (1u << 28) + (unsigned)(r_ * 65536.0f + 0.5f); \
                atomicAdd(&s_evcnt[rel_], enc_);                          \
            }                                                             \
        } }

        const unsigned* pp = packed + begin;
        for (int base = tid * 8; base + 7 < span; base += PTHR * 8) {
            uint4 A = *(const uint4*)(pp + base);
            uint4 B = *(const uint4*)(pp + base + 4);
            PROC1(A.x) PROC1(A.y) PROC1(A.z) PROC1(A.w)
            PROC1(B.x) PROC1(B.y) PROC1(B.z) PROC1(B.w)
        }
        for (int i = (span & ~7) + tid; i < span; i += PTHR) {
            unsigned P = pp[i];
            PROC1(P)
        }
        __syncthreads();   // all LDS atomics done

        // flush: f16(all)|f16(ev) u32 + u8 count
        char* sb = slices + (size_t)slice * PER_SLICE;
        unsigned*      wab = (unsigned*)(sb + SLICE_AB);
        unsigned char* wc  = (unsigned char*)(sb + SLICE_CNT);
        for (int i = tid; i < RBINS; i += PTHR) {
            float a = s_all[i];
            unsigned ec = s_evcnt[i];
            float e = (float)(ec & 0x0FFFFFFFu) * (1.0f / 65536.0f);
            unsigned ab = (unsigned)__half_as_ushort(__float2half(a))
                        | ((unsigned)__half_as_ushort(__float2half(e)) << 16);
            wab[rbase + i] = ab;
            wc[rbase + i]  = (unsigned char)(ec >> 28);
        }
    }
    __threadfence();
    grid.sync();

    // ================= phase C: fold slices (regs) + gsum; block NG2 folds scalars =================
    float va = 0.f, ve = 0.f; int vc = 0;
    int t = bid * PTHR + tid;             // bin id, valid for bid < NG2
    if (bid < NG2 && t < TBINS) {
        for (int s = 0; s < NS; ++s) {
            const char* sb = slices + (size_t)s * PER_SLICE;
            unsigned ab = ((const unsigned*)(sb + SLICE_AB))[t];
            va += __half2float(__ushort_as_half((unsigned short)(ab & 0xFFFFu)));
            ve += __half2float(__ushort_as_half((unsigned short)(ab >> 16)));
            vc += ((const unsigned char*)(sb + SLICE_CNT))[t];
        }
    }
    {
        float g = va;
        #pragma unroll
        for (int off = 32; off > 0; off >>= 1) g += __shfl_down(g, off, 64);
        __syncthreads();                 // red_f reuse
        if (lane == 0) red_f[wv] = g;
        __syncthreads();
        if (tid == 0 && bid < NG2) {
            float s = 0.f;
            #pragma unroll
            for (int w = 0; w < 16; ++w) s += red_f[w];
            gsum[bid] = s;
        }
    }
    if (bid == NG2) {
        float pl = (tid < NBLK) ? lrp[tid] : 0.f;
        int   pn = (tid < NBLK) ? np[tid]  : 0;
        #pragma unroll
        for (int off = 32; off > 0; off >>= 1) {
            pl += __shfl_down(pl, off, 64);
            pn += __shfl_down(pn, off, 64);
        }
        __syncthreads();
        if (lane == 0) { red_f[wv] = pl; red_i[wv] = pn; }
        __syncthreads();
        if (tid == 0) {
            float s = 0.f; int n = 0;
            #pragma unroll
            for (int w = 0; w < 16; ++w) { s += red_f[w]; n += red_i[w]; }
            scal[0] = (double)s;
            scal[1] = 0.0;
            *nev    = n;
        }
    }
    __threadfence();
    grid.sync();

    // ================= phase D: prefix-scan + Efron loss =================
    if (bid < NG2) {
        if (wv == 0) {
            float gg = (lane < bid) ? gsum[lane] : 0.f;   // bid <= 48 < 64
            #pragma unroll
            for (int off = 32; off > 0; off >>= 1) gg += __shfl_down(gg, off, 64);
            if (lane == 0) sh_base = gg;
        }
        __syncthreads();
        float x = va;
        #pragma unroll
        for (int off = 1; off < 64; off <<= 1) {
            float y = __shfl_up(x, off, 64);
            if (lane >= off) x += y;
        }
        if (lane == 63) red_f[wv] = x;
        __syncthreads();
        float wb = 0.f;
        for (int w = 0; w < wv; ++w) wb += red_f[w];
        float prefix = sh_base + wb + (x - va);   // risk over times strictly < t

        float acc = 0.f;
        if (t < TBINS && vc > 0) {
            float D  = ve;
            float nf = (float)vc;
            float P  = D + (va - D) * (nf / (nf + 1.f));  // E[partial risk]
            float R  = prefix + P;
            for (int j = 0; j < vc; ++j) {
                float arg = R - ((float)j / nf) * D + EPSF;
                acc += __logf(arg);
            }
        }
        __syncthreads();                 // red_f reuse
        #pragma unroll
        for (int off = 32; off > 0; off >>= 1) acc += __shfl_down(acc, off, 64);
        if (lane == 0) red_f[wv] = acc;
        __syncthreads();
        if (tid == 0) {
            float s = 0.f;
            #pragma unroll
            for (int w = 0; w < 16; ++w) s += red_f[w];
            atomicAdd(&scal[1], (double)s);
        }
    }
    __threadfence();
    grid.sync();

    // ================= phase E: finalize =================
    if (bid == 0 && tid == 0) {
        int n = *nev;
        out[0] = (n > 0) ? (float)((scal[1] - scal[0]) / (double)n) : 0.f;
    }
}

extern "C" void kernel_launch(void* const* d_in, const int* in_sizes, int n_in,
                              void* d_out, int out_size, void* d_ws, size_t ws_size,
                              hipStream_t stream) {
    const float* lr = (const float*)d_in[0];
    const int*   tm = (const int*)d_in[1];
    const int*   ev = (const int*)d_in[2];
    int N = in_sizes[0];
    char*  ws  = (char*)d_ws;
    float* out = (float*)d_out;

    void* kargs[] = { (void*)&lr, (void*)&tm, (void*)&ev, (void*)&N,
                      (void*)&ws, (void*)&out };
    hipLaunchCooperativeKernel((void*)k_fused, dim3(NBLK), dim3(PTHR),
                               kargs, 0, stream);
}

// Round 8
// 75.069 us; speedup vs baseline: 6.4374x; 6.4374x over previous
//
#include <hip/hip_runtime.h>
#include <hip/hip_fp16.h>
#include <math.h>

#define TBINS   50000
#define NR      4
#define RBINS   12500          // TBINS / NR
#define GROUP   256
#define NGROUPS 196            // ceil(TBINS / GROUP)
#define EPSF    1e-7f
#define NPB     256            // partition blocks
#define NWV     16             // waves per partition block (1024 thr)
#define NSL     64             // pass slices (each covers NPB/NSL=4 part blocks)
#define PER_SLICE 256000       // u32 ab[TBINS] (200000) + u8 cnt[TBINS] (50000), padded

// ---- ws layout (byte offsets) ----
#define OFF_SCAL  0            // dbl[2]: [0]=sum lr over events, [1]=log-sum
#define OFF_NEV   16           // int
#define OFF_DONE  20           // int (k_loss finalize ticket)
#define OFF_GSUM  64           // f32[NGROUPS]
#define OFF_ALLG  2048         // f32[TBINS]
#define OFF_EVG   202048       // f32[TBINS]
#define OFF_CNTG  402048       // i32[TBINS]
#define OFF_LRP   602048       // f32[NPB]
#define OFF_NP    603072       // i32[NPB]
#define OFF_CNTS  604160       // u32[NPB*NWV*4]
#define OFF_PART  669696       // u32[NPB*NWV*4*WCH]

// ============ k_part: read raw once, pack+partition into per-(blk,wave,range) segments ============
__global__ __launch_bounds__(1024) void k_part(
        const float* __restrict__ lr, const int* __restrict__ tm,
        const int* __restrict__ ev, int N, int WCH,
        unsigned* __restrict__ part, unsigned* __restrict__ cnts,
        float* __restrict__ lrp, int* __restrict__ np) {
    __shared__ float red_f[16];
    __shared__ int   red_i[16];
    const int b = blockIdx.x, tid = threadIdx.x;
    const int w = tid >> 6, lane = tid & 63;
    const unsigned long long lmask = (1ULL << lane) - 1ULL;

    const int base0 = (b * NWV + w) * WCH;
    const unsigned seg0 = (unsigned)(b * NWV + w) * 4u;
    unsigned wc0 = 0, wc1 = 0, wc2 = 0, wc3 = 0;
    float l_lr = 0.f; int l_n = 0;

    // one element: pack, route by range via wave ballot (wave-private positions, no atomics)
#define PART1(L, T, E, VALID) {                                           \
        float r_ = __expf(L);                                             \
        unsigned hb_ = (unsigned)__half_as_ushort(__float2half(r_));      \
        bool ve_ = (VALID) && ((E) != 0);                                 \
        if (ve_) { hb_ |= 0x8000u; l_lr += (L); l_n++; }                  \
        unsigned P_  = ((unsigned)(T) << 16) | hb_;                       \
        unsigned rg_ = ((unsigned)(T)) / 12500u;                          \
        { unsigned long long m_ = __ballot((VALID) && rg_ == 0u);         \
          if ((VALID) && rg_ == 0u)                                       \
              part[(size_t)(seg0 + 0u) * WCH + wc0 + (unsigned)__popcll(m_ & lmask)] = P_; \
          wc0 += (unsigned)__popcll(m_); }                                \
        { unsigned long long m_ = __ballot((VALID) && rg_ == 1u);         \
          if ((VALID) && rg_ == 1u)                                       \
              part[(size_t)(seg0 + 1u) * WCH + wc1 + (unsigned)__popcll(m_ & lmask)] = P_; \
          wc1 += (unsigned)__popcll(m_); }                                \
        { unsigned long long m_ = __ballot((VALID) && rg_ == 2u);         \
          if ((VALID) && rg_ == 2u)                                       \
              part[(size_t)(seg0 + 2u) * WCH + wc2 + (unsigned)__popcll(m_ & lmask)] = P_; \
          wc2 += (unsigned)__popcll(m_); }                                \
        { unsigned long long m_ = __ballot((VALID) && rg_ == 3u);         \
          if ((VALID) && rg_ == 3u)                                       \
              part[(size_t)(seg0 + 3u) * WCH + wc3 + (unsigned)__popcll(m_ & lmask)] = P_; \
          wc3 += (unsigned)__popcll(m_); }                                \
    }

    for (int it = 0; it < WCH; it += 256) {
        int idx = base0 + it + lane * 4;
        float4 l4 = {0.f, 0.f, 0.f, 0.f};
        int4   t4 = {0, 0, 0, 0};
        int4   e4 = {0, 0, 0, 0};
        if (idx + 3 < N) {
            l4 = *(const float4*)(lr + idx);
            t4 = *(const int4*)(tm + idx);
            e4 = *(const int4*)(ev + idx);
        } else if (idx < N) {
            float* lp = (float*)&l4; int* tp = (int*)&t4; int* ep = (int*)&e4;
            for (int k = 0; k < 4 && idx + k < N; ++k) {
                lp[k] = lr[idx + k]; tp[k] = tm[idx + k]; ep[k] = ev[idx + k];
            }
        }
        PART1(l4.x, t4.x, e4.x, (idx + 0) < N)
        PART1(l4.y, t4.y, e4.y, (idx + 1) < N)
        PART1(l4.z, t4.z, e4.z, (idx + 2) < N)
        PART1(l4.w, t4.w, e4.w, (idx + 3) < N)
    }

    if (lane == 0) {
        unsigned* c = cnts + seg0;
        c[0] = wc0; c[1] = wc1; c[2] = wc2; c[3] = wc3;
    }

    // block event scalars
    #pragma unroll
    for (int off = 32; off > 0; off >>= 1) {
        l_lr += __shfl_down(l_lr, off, 64);
        l_n  += __shfl_down(l_n,  off, 64);
    }
    if (lane == 0) { red_f[w] = l_lr; red_i[w] = l_n; }
    __syncthreads();
    if (tid == 0) {
        float s = 0.f; int c = 0;
        #pragma unroll
        for (int i = 0; i < NWV; ++i) { s += red_f[i]; c += red_i[i]; }
        lrp[b] = s; np[b] = c;
    }
}

// ============ k_pass: single-visit LDS histogram per (range, slice) ============
__global__ __launch_bounds__(1024) void k_pass(
        const unsigned* __restrict__ part, const unsigned* __restrict__ cnts,
        int WCH, char* __restrict__ slices) {
    __shared__ float    s_all[RBINS];
    __shared__ unsigned s_evcnt[RBINS];   // (count<<28) | fixed12.16(sum exp over events)
    const int bid = blockIdx.x;
    const int r = bid & 3, s = bid >> 2;
    const unsigned rbase = (unsigned)(r * RBINS);
    const int tid = threadIdx.x, w = tid >> 6, lane = tid & 63;

    for (int i = tid; i < RBINS; i += 1024) { s_all[i] = 0.f; s_evcnt[i] = 0u; }
    __syncthreads();

    // 64 segments feed this block: part-blocks [4s,4s+4) x 16 waves; wave w takes 4 of them
    for (int sl = w; sl < 4 * NWV; sl += NWV) {
        int pb = 4 * s + (sl >> 4);
        int pw = sl & 15;
        unsigned seg = (unsigned)(pb * NWV + pw) * 4u + (unsigned)r;
        unsigned cnt = cnts[seg];
        const unsigned* sp = part + (size_t)seg * WCH;
        for (unsigned i = (unsigned)lane; i < cnt; i += 64u) {
            unsigned P = sp[i];
            unsigned rel = (P >> 16) - rbase;
            if (rel < (unsigned)RBINS) {
                float r_ = __half2float(__ushort_as_half((unsigned short)(P & 0x7FFFu)));
                atomicAdd(&s_all[rel], r_);
                if (P & 0x8000u) {
                    unsigned enc = (1u << 28) + (unsigned)(r_ * 65536.0f + 0.5f);
                    atomicAdd(&s_evcnt[rel], enc);
                }
            }
        }
    }
    __syncthreads();

    // flush: f16(all)|f16(ev) + u8 count
    char* sb = slices + (size_t)s * PER_SLICE;
    unsigned*      wab = (unsigned*)sb;
    unsigned char* wcq = (unsigned char*)(sb + 200000);
    for (int i = tid; i < RBINS; i += 1024) {
        float a = s_all[i];
        unsigned ec = s_evcnt[i];
        float e = (float)(ec & 0x0FFFFFFFu) * (1.0f / 65536.0f);
        wab[rbase + i] = (unsigned)__half_as_ushort(__float2half(a))
                       | ((unsigned)__half_as_ushort(__float2half(e)) << 16);
        wcq[rbase + i] = (unsigned char)(ec >> 28);
    }
}

// ============ k_reduce: fold NSL slices; gsum; block 0 folds scalars + inits ============
__global__ __launch_bounds__(256) void k_reduce(const char* __restrict__ slices,
                                                const float* __restrict__ lrp,
                                                const int* __restrict__ np,
                                                float* all_g, float* ev_g, int* cnt_g,
                                                float* gsum, double* scal, int* nev,
                                                int* done) {
    __shared__ float lds[4];
    __shared__ float ldsf2[4];
    __shared__ int   ldsi2[4];
    int tid = threadIdx.x;
    int b = blockIdx.x * 256 + tid;
    float a = 0.f, d = 0.f; int c = 0;
    if (b < TBINS) {
        for (int s = 0; s < NSL; ++s) {
            const char* sb = slices + (size_t)s * PER_SLICE;
            unsigned ab = ((const unsigned*)sb)[b];
            a += __half2float(__ushort_as_half((unsigned short)(ab & 0xFFFFu)));
            d += __half2float(__ushort_as_half((unsigned short)(ab >> 16)));
            c += ((const unsigned char*)(sb + 200000))[b];
        }
        all_g[b] = a; ev_g[b] = d; cnt_g[b] = c;
    }
    int lane = tid & 63, wv = tid >> 6;
    float v = a;
    #pragma unroll
    for (int off = 32; off > 0; off >>= 1) v += __shfl_down(v, off, 64);
    if (lane == 0) lds[wv] = v;
    __syncthreads();
    if (tid == 0) {
        float s = 0.f;
        #pragma unroll
        for (int w = 0; w < 4; ++w) s += lds[w];
        gsum[blockIdx.x] = s;
    }

    if (blockIdx.x == 0) {
        float pl = lrp[tid];      // NPB == 256 == blockDim
        int   pn = np[tid];
        #pragma unroll
        for (int off = 32; off > 0; off >>= 1) {
            pl += __shfl_down(pl, off, 64);
            pn += __shfl_down(pn, off, 64);
        }
        if (lane == 0) { ldsf2[wv] = pl; ldsi2[wv] = pn; }
        __syncthreads();
        if (tid == 0) {
            float s = 0.f; int n = 0;
            #pragma unroll
            for (int w = 0; w < 4; ++w) { s += ldsf2[w]; n += ldsi2[w]; }
            scal[0] = (double)s;
            scal[1] = 0.0;
            *nev    = n;
            *done   = 0;
        }
    }
}

// ============ k_loss: prefix-scan + Efron loss; last block finalizes ============
__global__ __launch_bounds__(256) void k_loss(
        const float* __restrict__ all_g, const float* __restrict__ gsum,
        const int* __restrict__ cnt_g, const float* __restrict__ ev_g,
        double* scal, const int* __restrict__ nev, int* done,
        float* __restrict__ out) {
    __shared__ float lds_r[4];
    __shared__ float lds_s[4];
    __shared__ float sh_base;
    int b   = blockIdx.x;
    int tid = threadIdx.x;
    int t   = b * GROUP + tid;
    int lane = tid & 63, wv = tid >> 6;

    float gv = (tid < b) ? gsum[tid] : 0.f;   // b <= 195 < 256
    float red = gv;
    #pragma unroll
    for (int off = 32; off > 0; off >>= 1) red += __shfl_down(red, off, 64);
    if (lane == 0) lds_r[wv] = red;
    __syncthreads();
    if (tid == 0) {
        float s = 0.f;
        #pragma unroll
        for (int w = 0; w < 4; ++w) s += lds_r[w];
        sh_base = s;
    }
    __syncthreads();
    float base = sh_base;

    float v = (t < TBINS) ? all_g[t] : 0.f;
    float x = v;
    #pragma unroll
    for (int off = 1; off < 64; off <<= 1) {
        float y = __shfl_up(x, off, 64);
        if (lane >= off) x += y;
    }
    if (lane == 63) lds_s[wv] = x;
    __syncthreads();
    float wb = 0.f;
    for (int w = 0; w < wv; ++w) wb += lds_s[w];
    float prefix = base + wb + (x - v);       // risk over times strictly < t

    float acc = 0.f;
    if (t < TBINS) {
        int n = cnt_g[t];
        if (n > 0) {
            float D  = ev_g[t];
            float nf = (float)n;
            float P  = D + (v - D) * (nf / (nf + 1.f));   // E[partial risk]
            float R  = prefix + P;
            for (int j = 0; j < n; ++j) {
                float arg = R - ((float)j / nf) * D + EPSF;
                acc += __logf(arg);
            }
        }
    }
    __syncthreads();
    #pragma unroll
    for (int off = 32; off > 0; off >>= 1) acc += __shfl_down(acc, off, 64);
    if (lane == 0) lds_r[wv] = acc;
    __syncthreads();
    if (tid == 0) {
        float s = 0.f;
        #pragma unroll
        for (int w = 0; w < 4; ++w) s += lds_r[w];
        atomicAdd(&scal[1], (double)s);
        __threadfence();
        int ticket = atomicAdd(done, 1);
        if (ticket == NGROUPS - 1) {
            double logsum = atomicAdd(&scal[1], 0.0);   // coherent read of final sum
            int n = *nev;
            out[0] = (n > 0) ? (float)((logsum - scal[0]) / (double)n) : 0.f;
        }
    }
}

extern "C" void kernel_launch(void* const* d_in, const int* in_sizes, int n_in,
                              void* d_out, int out_size, void* d_ws, size_t ws_size,
                              hipStream_t stream) {
    const float* lr = (const float*)d_in[0];
    const int*   tm = (const int*)d_in[1];
    const int*   ev = (const int*)d_in[2];
    int N = in_sizes[0];

    char*     ws    = (char*)d_ws;
    double*   scal  = (double*)(ws + OFF_SCAL);
    int*      nev   = (int*)(ws + OFF_NEV);
    int*      done  = (int*)(ws + OFF_DONE);
    float*    gsum  = (float*)(ws + OFF_GSUM);
    float*    all_g = (float*)(ws + OFF_ALLG);
    float*    ev_g  = (float*)(ws + OFF_EVG);
    int*      cnt_g = (int*)(ws + OFF_CNTG);
    float*    lrp   = (float*)(ws + OFF_LRP);
    int*      np    = (int*)(ws + OFF_NP);
    unsigned* cnts  = (unsigned*)(ws + OFF_CNTS);
    unsigned* part  = (unsigned*)(ws + OFF_PART);

    // wave chunk, multiple of 256 elems
    int WCH = (int)((((long long)N + (NPB * NWV) - 1) / (NPB * NWV) + 255) / 256) * 256;
    size_t part_bytes = (size_t)NPB * NWV * 4 * WCH * 4;
    char* slices = ws + OFF_PART + part_bytes;   // NSL * PER_SLICE = 16.4 MB

    k_part<<<NPB, 1024, 0, stream>>>(lr, tm, ev, N, WCH, part, cnts, lrp, np);
    k_pass<<<NR * NSL, 1024, 0, stream>>>(part, cnts, WCH, slices);
    k_reduce<<<NGROUPS, 256, 0, stream>>>(slices, lrp, np, all_g, ev_g, cnt_g,
                                          gsum, scal, nev, done);
    k_loss<<<NGROUPS, 256, 0, stream>>>(all_g, gsum, cnt_g, ev_g, scal, nev, done,
                                        (float*)d_out);
}